// Round 11
// baseline (125.794 us; speedup 1.0000x reference)
//
#include <hip/hip_runtime.h>
#include <hip/hip_fp16.h>
#include <cmath>

#define NSPEC 119
#define FEAT 360
#define CAP 128          // max edges per atom bucket (mean 50, P(overflow) ~ 1e-20)
#define G 16             // lanes cooperating per atom in accum
#define NPAIR (NSPEC*NSPEC*35)   // 495635 source elements
#define CNTSTRIDE 16     // one counter per 64-B line
// ws layout:
//   cnt    int[n_atoms*16]        @ 0          (640 KB, 64-B stride counters; memsetAsync 0)
//   emb_h  __half[14161*64]       @ 655360     (128-B stride rows, 2 lines each)
//   pre8   int2[n_edges]          @ 2467968    ({pi<<14|aj, slot or -1}, coalesced)
//   bucket uint4[n_atoms*CAP]     @ 6467968    (20.5 MB, 16-B records)
// bucket record: 8 f16 = [rad0..rad4, dx, dy, dz]
// M layout (regs + LDS slot): [0..4]=M0, [5..19]=M1 (r*3+i),
// [20..49]=M2 unique (r*6+u), [50..99]=M3 unique (r*10+u)

// ---- K1: emb -> f16 rows; per-edge pair-pack + slot assignment (atomic) ----
__global__ __launch_bounds__(256) void gm_prep_kernel(
    const float* __restrict__ emb, __half* __restrict__ emb_h,
    const int* __restrict__ Z, const int* __restrict__ nbr,
    int2* __restrict__ pre8, int* __restrict__ cnt,
    int n_atoms, int n_edges)
{
    int t = blockIdx.x * 256 + threadIdx.x;
    if (t < NPAIR) {
        int p = t / 35;
        int b = t - p * 35;
        emb_h[(p << 6) + b] = __float2half_rn(emb[t]);
    }
    if (t < n_edges) {
        int ai = nbr[t];
        int aj = nbr[n_edges + t];
        int pi = Z[ai] * NSPEC + Z[aj];         // Z: 40 KB, cache-hot
        int pos = atomicAdd(&cnt[aj * CNTSTRIDE], 1);
        int slot = (pos < CAP) ? (aj * CAP + pos) : -1;
        pre8[t] = make_int2((pi << 14) | aj, slot);
    }
}

// ---- K2: scatter — all-coalesced in, ONE random gather + ONE random store --
__global__ __launch_bounds__(256) void gm_scatter_kernel(
    const float* __restrict__ dr_vec,
    const int2* __restrict__ pre8,
    const __half* __restrict__ emb_h,
    uint4* __restrict__ bucket,
    int n_edges, float rad_norm)
{
    int e = blockIdx.x * 256 + threadIdx.x;
    if (e >= n_edges) return;

    int2 pk = pre8[e];               // coalesced 8 B
    int pi   = pk.x >> 14;
    int slot = pk.y;

    // the only dependent random round: emb row (2 lines)
    const uint4* p4 = (const uint4*)(emb_h + ((size_t)pi << 6));
    uint buf[20];
#pragma unroll
    for (int q = 0; q < 5; ++q) *(uint4*)(buf + 4*q) = p4[q];

    float x = dr_vec[3*e+0];         // coalesced
    float y = dr_vec[3*e+1];
    float z = dr_vec[3*e+2];

    float dr = sqrtf(x*x + y*y + z*z);
    float inv = 1.0f / (dr + 1e-5f);
    float dx = x*inv, dy = y*inv, dz = z*inv;

    const float betta = 49.0f/36.0f;
    float basis[7];
#pragma unroll
    for (int b = 0; b < 7; ++b) {
        float tt = dr - (0.5f + (5.5f/7.0f)*(float)b);
        basis[b] = rad_norm * __expf(-betta*tt*tt);
    }
    float cutoff = 0.5f * (__cosf(fminf(dr, 6.0f) * 0.52359877559829887f) + 1.0f);
    float sc = cutoff * 0.37796447300922720f; // 1/sqrt(7)

    const __half2* hb = (const __half2*)buf;
    float co[36];
#pragma unroll
    for (int q = 0; q < 18; ++q) {
        float2 f = __half22float2(hb[q]);
        co[2*q]   = f.x;
        co[2*q+1] = f.y;
    }

    float rad[5];
#pragma unroll
    for (int r = 0; r < 5; ++r) {
        float acc = 0.0f;
#pragma unroll
        for (int b = 0; b < 7; ++b) acc = fmaf(co[r*7+b], basis[b], acc);
        rad[r] = acc * sc;
    }

    if (slot >= 0) {
        uint4 rec;
        __half2* rp = (__half2*)&rec;
        rp[0] = __float22half2_rn(make_float2(rad[0], rad[1]));
        rp[1] = __float22half2_rn(make_float2(rad[2], rad[3]));
        rp[2] = __float22half2_rn(make_float2(rad[4], dx));
        rp[3] = __float22half2_rn(make_float2(dy, dz));
        bucket[slot] = rec;
    }
}

// ---- K3: fused moment accumulation + tensor contraction --------------------
__global__ __launch_bounds__(256) void gm_accum_kernel(
    const int* __restrict__ cnt,
    const uint4* __restrict__ bucket,
    float* __restrict__ out,
    int n_atoms)
{
    __shared__ float MS[16][100];
    int tid = blockIdx.x * 256 + threadIdx.x;
    int a  = tid / G;
    int sl = tid & (G-1);
    int la = threadIdx.x >> 4;          // atom slot within block
    if (a >= n_atoms) return;

    int c = cnt[a * CNTSTRIDE]; if (c > CAP) c = CAP;

    float m[100];
#pragma unroll
    for (int i = 0; i < 100; ++i) m[i] = 0.f;

    for (int k = sl; k < c; k += G) {
        uint4 rec = bucket[(size_t)a * CAP + k];
        const __half2* rp = (const __half2*)&rec;
        float2 f0 = __half22float2(rp[0]);
        float2 f1 = __half22float2(rp[1]);
        float2 f2 = __half22float2(rp[2]);
        float2 f3 = __half22float2(rp[3]);
        float rad[5] = {f0.x, f0.y, f1.x, f1.y, f2.x};
        float dx = f2.y, dy = f3.x, dz = f3.y;

        float p2[6] = {dx*dx, dx*dy, dx*dz, dy*dy, dy*dz, dz*dz};
        float p3[10] = {p2[0]*dx, p2[0]*dy, p2[0]*dz,
                        p2[3]*dx, p2[4]*dx, p2[5]*dx,
                        p2[3]*dy, p2[3]*dz,
                        p2[4]*dz, p2[5]*dz};

#pragma unroll
        for (int r = 0; r < 5; ++r) {
            float v = rad[r];
            m[r] += v;
            m[5 + r*3 + 0] = fmaf(v, dx, m[5 + r*3 + 0]);
            m[5 + r*3 + 1] = fmaf(v, dy, m[5 + r*3 + 1]);
            m[5 + r*3 + 2] = fmaf(v, dz, m[5 + r*3 + 2]);
#pragma unroll
            for (int u = 0; u < 6; ++u)
                m[20 + r*6 + u] = fmaf(v, p2[u], m[20 + r*6 + u]);
#pragma unroll
            for (int u = 0; u < 10; ++u)
                m[50 + r*10 + u] = fmaf(v, p3[u], m[50 + r*10 + u]);
        }
    }

    // butterfly reduce across the 16 lanes (all lanes get the sum)
#pragma unroll
    for (int i = 0; i < 100; ++i) {
        m[i] += __shfl_xor(m[i], 1, 64);
        m[i] += __shfl_xor(m[i], 2, 64);
        m[i] += __shfl_xor(m[i], 4, 64);
        m[i] += __shfl_xor(m[i], 8, 64);
    }

    if (sl == 0) {
#pragma unroll
        for (int i = 0; i < 100; ++i) MS[la][i] = m[i];
    }
    // same-wave DS write->read, each group touches only its own slot.

    float* F = out + (size_t)a * FEAT;
    const float* S = &MS[la][0];

    const int S2[3][3] = {{0,1,2},{1,3,4},{2,4,5}};
    const int S3[3][3][3] = {
        {{0,1,2},{1,3,4},{2,4,5}},
        {{1,3,4},{3,6,7},{4,7,8}},
        {{2,4,5},{4,7,8},{5,8,9}}};
    const float w6[6]   = {1,2,2,1,2,1};
    const float w10[10] = {1,3,3,3,6,3,1,3,3,1};
    const int   PI[6] = {0,0,0,1,1,2};
    const int   PJ[6] = {0,1,2,1,2,2};
    const float PW[6] = {1,2,2,1,2,1};

    // c0
    if (sl < 5) F[sl] = S[sl];

    int p = sl;
    if (p < 15) {
        int r = (p >= 10) ? 4 : ((p >= 6) ? 3 : ((p >= 3) ? 2 : ((p >= 1) ? 1 : 0)));
        int s = p - (r*(r+1))/2;
        const float* M1r = S + 5  + 3*r;
        const float* M1s = S + 5  + 3*s;
        const float* M2r = S + 20 + 6*r;
        const float* M2s = S + 20 + 6*s;
        const float* M3r = S + 50 + 10*r;
        const float* M3s = S + 50 + 10*s;
        float m1r[3], m1s[3], m2r[6], m2s[6], m3r[10], m3s[10];
#pragma unroll
        for (int i = 0; i < 3; ++i)  { m1r[i] = M1r[i]; m1s[i] = M1s[i]; }
#pragma unroll
        for (int u = 0; u < 6; ++u)  { m2r[u] = M2r[u]; m2s[u] = M2s[u]; }
#pragma unroll
        for (int u = 0; u < 10; ++u) { m3r[u] = M3r[u]; m3s[u] = M3s[u]; }

        // c1, c2, c3
        float a1 = 0.f, a2 = 0.f, a3 = 0.f;
#pragma unroll
        for (int i = 0; i < 3; ++i)  a1 = fmaf(m1r[i], m1s[i], a1);
#pragma unroll
        for (int u = 0; u < 6; ++u)  a2 = fmaf(w6[u]*m2r[u],  m2s[u], a2);
#pragma unroll
        for (int u = 0; u < 10; ++u) a3 = fmaf(w10[u]*m3r[u], m3s[u], a3);
        F[5 + p]  = a1;
        F[20 + p] = a2;
        F[35 + p] = a3;

        // c4
        float P[3][3];
#pragma unroll
        for (int j = 0; j < 3; ++j)
#pragma unroll
        for (int k = 0; k < 3; ++k) {
            float acc = 0.f;
#pragma unroll
            for (int i = 0; i < 3; ++i)
                acc = fmaf(m2r[S2[i][j]], m2s[S2[i][k]], acc);
            P[j][k] = acc;
        }
        float PA[6] = {P[0][0], P[0][1]+P[1][0], P[0][2]+P[2][0],
                       P[1][1], P[1][2]+P[2][1], P[2][2]};
        int qb = (r*(r+1)*(r+2))/6 + (s*(s+1))/2;
        for (int t = 0; t <= s; ++t) {
            const float* M2t = S + 20 + 6*t;
            float acc = 0.f;
#pragma unroll
            for (int u = 0; u < 6; ++u) acc = fmaf(PA[u], M2t[u], acc);
            F[50 + qb + t] = acc;
        }

        // c5
        float A[6] = {m1r[0]*m1s[0],
                      m1r[0]*m1s[1] + m1r[1]*m1s[0],
                      m1r[0]*m1s[2] + m1r[2]*m1s[0],
                      m1r[1]*m1s[1],
                      m1r[1]*m1s[2] + m1r[2]*m1s[1],
                      m1r[2]*m1s[2]};
#pragma unroll
        for (int t = 0; t < 5; ++t) {
            const float* M2t = S + 20 + 6*t;
            float acc = 0.f;
#pragma unroll
            for (int u = 0; u < 6; ++u) acc = fmaf(A[u], M2t[u], acc);
            F[85 + p*5 + t] = acc;
        }

        // c6
        float Q[3][3];
#pragma unroll
        for (int k = 0; k < 3; ++k)
#pragma unroll
        for (int l = 0; l < 3; ++l) {
            float acc = 0.f;
#pragma unroll
            for (int u = 0; u < 6; ++u)
                acc = fmaf(PW[u]*m3r[S3[PI[u]][PJ[u]][k]],
                           m3s[S3[PI[u]][PJ[u]][l]], acc);
            Q[k][l] = acc;
        }
        float QA[6] = {Q[0][0], Q[0][1]+Q[1][0], Q[0][2]+Q[2][0],
                       Q[1][1], Q[1][2]+Q[2][1], Q[2][2]};
#pragma unroll
        for (int t = 0; t < 5; ++t) {
            const float* M2t = S + 20 + 6*t;
            float acc = 0.f;
#pragma unroll
            for (int u = 0; u < 6; ++u) acc = fmaf(QA[u], M2t[u], acc);
            F[160 + p*5 + t] = acc;
        }
    }

    // c7: full 5x5 (r,s) grid, pairs hp = sl and sl+16
#pragma unroll
    for (int hh = 0; hh < 2; ++hh) {
        int hp = sl + 16*hh;
        if (hp < 25) {
            int r = hp / 5;
            int s = hp - 5*r;
            const float* M3r = S + 50 + 10*r;
            const float* M2s = S + 20 + 6*s;
            float m3r[10], m2s[6];
#pragma unroll
            for (int u = 0; u < 10; ++u) m3r[u] = M3r[u];
#pragma unroll
            for (int u = 0; u < 6; ++u)  m2s[u] = M2s[u];
            float B[3];
#pragma unroll
            for (int k = 0; k < 3; ++k) {
                float acc = 0.f;
#pragma unroll
                for (int u = 0; u < 6; ++u)
                    acc = fmaf(PW[u]*m3r[S3[PI[u]][PJ[u]][k]], m2s[u], acc);
                B[k] = acc;
            }
#pragma unroll
            for (int t = 0; t < 5; ++t) {
                const float* M1t = S + 5 + 3*t;
                F[235 + r*25 + s*5 + t] =
                    fmaf(B[0], M1t[0], fmaf(B[1], M1t[1], B[2]*M1t[2]));
            }
        }
    }
}

extern "C" void kernel_launch(void* const* d_in, const int* in_sizes, int n_in,
                              void* d_out, int out_size, void* d_ws, size_t ws_size,
                              hipStream_t stream) {
    const float* dr_vec = (const float*)d_in[0];
    const int*   Z      = (const int*)d_in[1];
    const int*   nbr    = (const int*)d_in[2];
    const float* emb    = (const float*)d_in[3];
    float* out = (float*)d_out;

    int n_edges = in_sizes[0] / 3;
    int n_atoms = in_sizes[1];

    int*    cnt    = (int*)d_ws;
    __half* emb_h  = (__half*)((char*)d_ws + 655360);
    int2*   pre8   = (int2*)((char*)d_ws + 2467968);
    uint4*  bucket = (uint4*)((char*)d_ws + 6467968);

    float rad_norm = (float)pow(2.0 * (49.0/36.0) / M_PI, 0.75); // (2*betta/pi)^0.75

    // counters must be zero before prep's atomics
    hipMemsetAsync(cnt, 0, (size_t)n_atoms * CNTSTRIDE * sizeof(int), stream);

    int prep_n = NPAIR;
    if (n_edges > prep_n) prep_n = n_edges;
    gm_prep_kernel<<<(prep_n + 255)/256, 256, 0, stream>>>(
        emb, emb_h, Z, nbr, pre8, cnt, n_atoms, n_edges);

    gm_scatter_kernel<<<(n_edges + 255)/256, 256, 0, stream>>>(
        dr_vec, pre8, emb_h, bucket, n_edges, rad_norm);

    int accum_threads = n_atoms * G;
    gm_accum_kernel<<<(accum_threads + 255)/256, 256, 0, stream>>>(
        cnt, bucket, out, n_atoms);
}

// Round 12
// 119.583 us; speedup vs baseline: 1.0519x; 1.0519x over previous
//
#include <hip/hip_runtime.h>
#include <hip/hip_fp16.h>
#include <cmath>

#define NSPEC 119
#define FEAT 360
#define CAP 128          // max edges per atom bucket (mean 50, P(overflow) ~ 1e-20)
#define G 16             // lanes cooperating per atom in accum
#define NPAIR (NSPEC*NSPEC*35)   // 495635 source elements
#define CNTSTRIDE 16     // one counter per 64-B line
// ws layout:
//   cnt    int[n_atoms*16]        @ 0          (640 KB, 64-B stride counters)
//   emb_h  __half[14161*64]       @ 655360     (128-B stride rows, 2 lines each)
//   pre    int[n_edges]           @ 2467968    (packed pi<<14 | aj, coalesced)
//   bucket uint4[n_atoms*CAP]     @ 4467968    (20.5 MB, 16-B records)
// bucket record: 8 f16 = [rad0..rad4, dx, dy, dz]
// M layout (regs + LDS slot): [0..4]=M0, [5..19]=M1 (r*3+i),
// [20..49]=M2 unique (r*6+u), [50..99]=M3 unique (r*10+u)

// ---- K1: emb -> f16 padded rows; cnt = 0; pack (pair,aj) per edge ----------
__global__ __launch_bounds__(256) void gm_prep_kernel(
    const float* __restrict__ emb, __half* __restrict__ emb_h,
    const int* __restrict__ Z, const int* __restrict__ nbr,
    int* __restrict__ pre, int* __restrict__ cnt,
    int n_atoms, int n_edges)
{
    int t = blockIdx.x * 256 + threadIdx.x;
    if (t < NPAIR) {
        int p = t / 35;
        int b = t - p * 35;
        emb_h[(p << 6) + b] = __float2half_rn(emb[t]);
    }
    if (t < n_atoms) cnt[t * CNTSTRIDE] = 0;
    if (t < n_edges) {
        int ai = nbr[t];
        int aj = nbr[n_edges + t];
        int pi = Z[ai] * NSPEC + Z[aj];     // Z: 40 KB, L1/L2-hot
        pre[t] = (pi << 14) | aj;           // pi<=14160 (18 bits at <<14), aj<16384
    }
}

// ---- K2: scatter — coalesced reads, ONE dependent gather round -------------
__global__ __launch_bounds__(256) void gm_scatter_kernel(
    const float* __restrict__ dr_vec,
    const int* __restrict__ pre,
    const __half* __restrict__ emb_h,
    int* __restrict__ cnt,
    uint4* __restrict__ bucket,
    int n_edges, float rad_norm)
{
    int e = blockIdx.x * 256 + threadIdx.x;
    if (e >= n_edges) return;

    int pk = pre[e];                 // coalesced
    int aj = pk & 16383;
    int pi = pk >> 14;

    // independent long-latency ops issue together:
    int pos = atomicAdd(&cnt[aj * CNTSTRIDE], 1);
    const uint4* p4 = (const uint4*)(emb_h + ((size_t)pi << 6));
    uint buf[20];
#pragma unroll
    for (int q = 0; q < 5; ++q) *(uint4*)(buf + 4*q) = p4[q];

    float x = dr_vec[3*e+0];         // coalesced
    float y = dr_vec[3*e+1];
    float z = dr_vec[3*e+2];

    float dr = sqrtf(x*x + y*y + z*z);
    float inv = 1.0f / (dr + 1e-5f);
    float dx = x*inv, dy = y*inv, dz = z*inv;

    const float betta = 49.0f/36.0f;
    float basis[7];
#pragma unroll
    for (int b = 0; b < 7; ++b) {
        float tt = dr - (0.5f + (5.5f/7.0f)*(float)b);
        basis[b] = rad_norm * __expf(-betta*tt*tt);
    }
    float cutoff = 0.5f * (__cosf(fminf(dr, 6.0f) * 0.52359877559829887f) + 1.0f);
    float sc = cutoff * 0.37796447300922720f; // 1/sqrt(7)

    const __half2* hb = (const __half2*)buf;
    float co[36];
#pragma unroll
    for (int q = 0; q < 18; ++q) {
        float2 f = __half22float2(hb[q]);
        co[2*q]   = f.x;
        co[2*q+1] = f.y;
    }

    float rad[5];
#pragma unroll
    for (int r = 0; r < 5; ++r) {
        float acc = 0.0f;
#pragma unroll
        for (int b = 0; b < 7; ++b) acc = fmaf(co[r*7+b], basis[b], acc);
        rad[r] = acc * sc;
    }

    if (pos < CAP) {
        uint4 rec;
        __half2* rp = (__half2*)&rec;
        rp[0] = __float22half2_rn(make_float2(rad[0], rad[1]));
        rp[1] = __float22half2_rn(make_float2(rad[2], rad[3]));
        rp[2] = __float22half2_rn(make_float2(rad[4], dx));
        rp[3] = __float22half2_rn(make_float2(dy, dz));
        bucket[(size_t)aj * CAP + pos] = rec;
    }
}

// ---- K3: fused moment accumulation + tensor contraction --------------------
__global__ __launch_bounds__(256) void gm_accum_kernel(
    const int* __restrict__ cnt,
    const uint4* __restrict__ bucket,
    float* __restrict__ out,
    int n_atoms)
{
    __shared__ float MS[16][100];
    int tid = blockIdx.x * 256 + threadIdx.x;
    int a  = tid / G;
    int sl = tid & (G-1);
    int la = threadIdx.x >> 4;          // atom slot within block
    if (a >= n_atoms) return;

    int c = cnt[a * CNTSTRIDE]; if (c > CAP) c = CAP;

    float m[100];
#pragma unroll
    for (int i = 0; i < 100; ++i) m[i] = 0.f;

    for (int k = sl; k < c; k += G) {
        uint4 rec = bucket[(size_t)a * CAP + k];
        const __half2* rp = (const __half2*)&rec;
        float2 f0 = __half22float2(rp[0]);
        float2 f1 = __half22float2(rp[1]);
        float2 f2 = __half22float2(rp[2]);
        float2 f3 = __half22float2(rp[3]);
        float rad[5] = {f0.x, f0.y, f1.x, f1.y, f2.x};
        float dx = f2.y, dy = f3.x, dz = f3.y;

        float p2[6] = {dx*dx, dx*dy, dx*dz, dy*dy, dy*dz, dz*dz};
        float p3[10] = {p2[0]*dx, p2[0]*dy, p2[0]*dz,
                        p2[3]*dx, p2[4]*dx, p2[5]*dx,
                        p2[3]*dy, p2[3]*dz,
                        p2[4]*dz, p2[5]*dz};

#pragma unroll
        for (int r = 0; r < 5; ++r) {
            float v = rad[r];
            m[r] += v;
            m[5 + r*3 + 0] = fmaf(v, dx, m[5 + r*3 + 0]);
            m[5 + r*3 + 1] = fmaf(v, dy, m[5 + r*3 + 1]);
            m[5 + r*3 + 2] = fmaf(v, dz, m[5 + r*3 + 2]);
#pragma unroll
            for (int u = 0; u < 6; ++u)
                m[20 + r*6 + u] = fmaf(v, p2[u], m[20 + r*6 + u]);
#pragma unroll
            for (int u = 0; u < 10; ++u)
                m[50 + r*10 + u] = fmaf(v, p3[u], m[50 + r*10 + u]);
        }
    }

    // butterfly reduce across the 16 lanes (all lanes get the sum)
#pragma unroll
    for (int i = 0; i < 100; ++i) {
        m[i] += __shfl_xor(m[i], 1, 64);
        m[i] += __shfl_xor(m[i], 2, 64);
        m[i] += __shfl_xor(m[i], 4, 64);
        m[i] += __shfl_xor(m[i], 8, 64);
    }

    if (sl == 0) {
#pragma unroll
        for (int i = 0; i < 100; ++i) MS[la][i] = m[i];
    }
    // same-wave DS write->read, each group touches only its own slot.

    float* F = out + (size_t)a * FEAT;
    const float* S = &MS[la][0];

    const int S2[3][3] = {{0,1,2},{1,3,4},{2,4,5}};
    const int S3[3][3][3] = {
        {{0,1,2},{1,3,4},{2,4,5}},
        {{1,3,4},{3,6,7},{4,7,8}},
        {{2,4,5},{4,7,8},{5,8,9}}};
    const float w6[6]   = {1,2,2,1,2,1};
    const float w10[10] = {1,3,3,3,6,3,1,3,3,1};
    const int   PI[6] = {0,0,0,1,1,2};
    const int   PJ[6] = {0,1,2,1,2,2};
    const float PW[6] = {1,2,2,1,2,1};

    // c0
    if (sl < 5) F[sl] = S[sl];

    int p = sl;
    if (p < 15) {
        int r = (p >= 10) ? 4 : ((p >= 6) ? 3 : ((p >= 3) ? 2 : ((p >= 1) ? 1 : 0)));
        int s = p - (r*(r+1))/2;
        const float* M1r = S + 5  + 3*r;
        const float* M1s = S + 5  + 3*s;
        const float* M2r = S + 20 + 6*r;
        const float* M2s = S + 20 + 6*s;
        const float* M3r = S + 50 + 10*r;
        const float* M3s = S + 50 + 10*s;
        float m1r[3], m1s[3], m2r[6], m2s[6], m3r[10], m3s[10];
#pragma unroll
        for (int i = 0; i < 3; ++i)  { m1r[i] = M1r[i]; m1s[i] = M1s[i]; }
#pragma unroll
        for (int u = 0; u < 6; ++u)  { m2r[u] = M2r[u]; m2s[u] = M2s[u]; }
#pragma unroll
        for (int u = 0; u < 10; ++u) { m3r[u] = M3r[u]; m3s[u] = M3s[u]; }

        // c1, c2, c3
        float a1 = 0.f, a2 = 0.f, a3 = 0.f;
#pragma unroll
        for (int i = 0; i < 3; ++i)  a1 = fmaf(m1r[i], m1s[i], a1);
#pragma unroll
        for (int u = 0; u < 6; ++u)  a2 = fmaf(w6[u]*m2r[u],  m2s[u], a2);
#pragma unroll
        for (int u = 0; u < 10; ++u) a3 = fmaf(w10[u]*m3r[u], m3s[u], a3);
        F[5 + p]  = a1;
        F[20 + p] = a2;
        F[35 + p] = a3;

        // c4
        float P[3][3];
#pragma unroll
        for (int j = 0; j < 3; ++j)
#pragma unroll
        for (int k = 0; k < 3; ++k) {
            float acc = 0.f;
#pragma unroll
            for (int i = 0; i < 3; ++i)
                acc = fmaf(m2r[S2[i][j]], m2s[S2[i][k]], acc);
            P[j][k] = acc;
        }
        float PA[6] = {P[0][0], P[0][1]+P[1][0], P[0][2]+P[2][0],
                       P[1][1], P[1][2]+P[2][1], P[2][2]};
        int qb = (r*(r+1)*(r+2))/6 + (s*(s+1))/2;
        for (int t = 0; t <= s; ++t) {
            const float* M2t = S + 20 + 6*t;
            float acc = 0.f;
#pragma unroll
            for (int u = 0; u < 6; ++u) acc = fmaf(PA[u], M2t[u], acc);
            F[50 + qb + t] = acc;
        }

        // c5
        float A[6] = {m1r[0]*m1s[0],
                      m1r[0]*m1s[1] + m1r[1]*m1s[0],
                      m1r[0]*m1s[2] + m1r[2]*m1s[0],
                      m1r[1]*m1s[1],
                      m1r[1]*m1s[2] + m1r[2]*m1s[1],
                      m1r[2]*m1s[2]};
#pragma unroll
        for (int t = 0; t < 5; ++t) {
            const float* M2t = S + 20 + 6*t;
            float acc = 0.f;
#pragma unroll
            for (int u = 0; u < 6; ++u) acc = fmaf(A[u], M2t[u], acc);
            F[85 + p*5 + t] = acc;
        }

        // c6
        float Q[3][3];
#pragma unroll
        for (int k = 0; k < 3; ++k)
#pragma unroll
        for (int l = 0; l < 3; ++l) {
            float acc = 0.f;
#pragma unroll
            for (int u = 0; u < 6; ++u)
                acc = fmaf(PW[u]*m3r[S3[PI[u]][PJ[u]][k]],
                           m3s[S3[PI[u]][PJ[u]][l]], acc);
            Q[k][l] = acc;
        }
        float QA[6] = {Q[0][0], Q[0][1]+Q[1][0], Q[0][2]+Q[2][0],
                       Q[1][1], Q[1][2]+Q[2][1], Q[2][2]};
#pragma unroll
        for (int t = 0; t < 5; ++t) {
            const float* M2t = S + 20 + 6*t;
            float acc = 0.f;
#pragma unroll
            for (int u = 0; u < 6; ++u) acc = fmaf(QA[u], M2t[u], acc);
            F[160 + p*5 + t] = acc;
        }
    }

    // c7: full 5x5 (r,s) grid, pairs hp = sl and sl+16
#pragma unroll
    for (int hh = 0; hh < 2; ++hh) {
        int hp = sl + 16*hh;
        if (hp < 25) {
            int r = hp / 5;
            int s = hp - 5*r;
            const float* M3r = S + 50 + 10*r;
            const float* M2s = S + 20 + 6*s;
            float m3r[10], m2s[6];
#pragma unroll
            for (int u = 0; u < 10; ++u) m3r[u] = M3r[u];
#pragma unroll
            for (int u = 0; u < 6; ++u)  m2s[u] = M2s[u];
            float B[3];
#pragma unroll
            for (int k = 0; k < 3; ++k) {
                float acc = 0.f;
#pragma unroll
                for (int u = 0; u < 6; ++u)
                    acc = fmaf(PW[u]*m3r[S3[PI[u]][PJ[u]][k]], m2s[u], acc);
                B[k] = acc;
            }
#pragma unroll
            for (int t = 0; t < 5; ++t) {
                const float* M1t = S + 5 + 3*t;
                F[235 + r*25 + s*5 + t] =
                    fmaf(B[0], M1t[0], fmaf(B[1], M1t[1], B[2]*M1t[2]));
            }
        }
    }
}

extern "C" void kernel_launch(void* const* d_in, const int* in_sizes, int n_in,
                              void* d_out, int out_size, void* d_ws, size_t ws_size,
                              hipStream_t stream) {
    const float* dr_vec = (const float*)d_in[0];
    const int*   Z      = (const int*)d_in[1];
    const int*   nbr    = (const int*)d_in[2];
    const float* emb    = (const float*)d_in[3];
    float* out = (float*)d_out;

    int n_edges = in_sizes[0] / 3;
    int n_atoms = in_sizes[1];

    int*    cnt    = (int*)d_ws;
    __half* emb_h  = (__half*)((char*)d_ws + 655360);
    int*    pre    = (int*)((char*)d_ws + 2467968);
    uint4*  bucket = (uint4*)((char*)d_ws + 4467968);

    float rad_norm = (float)pow(2.0 * (49.0/36.0) / M_PI, 0.75); // (2*betta/pi)^0.75

    int prep_n = NPAIR;
    if (n_edges > prep_n) prep_n = n_edges;
    if (n_atoms > prep_n) prep_n = n_atoms;
    gm_prep_kernel<<<(prep_n + 255)/256, 256, 0, stream>>>(
        emb, emb_h, Z, nbr, pre, cnt, n_atoms, n_edges);

    gm_scatter_kernel<<<(n_edges + 255)/256, 256, 0, stream>>>(
        dr_vec, pre, emb_h, cnt, bucket, n_edges, rad_norm);

    int accum_threads = n_atoms * G;
    gm_accum_kernel<<<(accum_threads + 255)/256, 256, 0, stream>>>(
        cnt, bucket, out, n_atoms);
}